// Round 13
// baseline (146.231 us; speedup 1.0000x reference)
//
#include <hip/hip_runtime.h>
#include <cfloat>
#include <stdint.h>

#define B_   16
#define N_   2048
#define KK   10          // window = K+1
#define H_   128
#define SUB  32          // chunk size
#define NCH  (N_ / SUB)  // 64 chunks

#define RANK_BLOCKS (B_ * 32)                  // 512: 64-elem segments, 256 thr
#define WEFF_OUT    (H_ * KK * 2 + H_)         // 2688 outputs
#define WEFF_BLOCKS ((WEFF_OUT * 4) / 256)     // 42 (4 lanes/output, exact)

__device__ inline uint32_t f32_ordered(float f) {
    uint32_t u = __float_as_uint(f);
    return (u & 0x80000000u) ? ~u : (u | 0x80000000u);
}

// ---- setup (unchanged, ~6us): rank-by-count sort; unique keys ->
// exact permutation, output bitwise-identical to the original bitonic.
__global__ __launch_bounds__(256) void setup_kernel(
    const float* __restrict__ x,
    const float* __restrict__ Wconv, const float* __restrict__ bconv,
    const float* __restrict__ b1,    const float* __restrict__ W2,
    const float* __restrict__ b2,
    float4* __restrict__ xsorted,    // [B][N] (px,py,sm,orig_idx_bits)
    float*  __restrict__ weff,       // [H*20]
    float*  __restrict__ btot)       // [H]
{
#pragma clang fp contract(off)
    __shared__ __align__(16) uint64_t sk[N_];   // 16 KB
    __shared__ int pcnt[4 * 64];
    const int tid = threadIdx.x;

    if (blockIdx.x >= RANK_BLOCKS) {
        const int g = (blockIdx.x - RANK_BLOCKS) * 256 + tid;
        const int o = g >> 2, q = g & 3;
        float acc = 0.f;
        if (o < H_ * KK * 2) {
            const int e = o / 20, r = o % 20, k = r >> 1, c = r & 1;
            const float* w2p = W2 + e * H_ + q * 32;
            const float* wcp = Wconv + (q * 32) * (2 * KK) + c * KK + k;
#pragma unroll 8
            for (int h = 0; h < 32; ++h)
                acc += w2p[h] * wcp[h * (2 * KK)];
        } else {
            const int e = o - H_ * KK * 2;
            const float* w2p = W2 + e * H_ + q * 32;
            const float* bcp = bconv + q * 32;
#pragma unroll 8
            for (int h = 0; h < 32; ++h) acc += w2p[h] * bcp[h];
        }
        acc += __shfl_xor(acc, 1, 64);
        acc += __shfl_xor(acc, 2, 64);
        if (q == 0) {
            if (o < H_ * KK * 2) weff[o] = acc;
            else {
                const int e = o - H_ * KK * 2;
                btot[e] = acc + b1[e] + b2[e];
            }
        }
        return;
    }

    const int b  = blockIdx.x >> 5;
    const int sg = blockIdx.x & 31;
    const float2* xb = (const float2*)(x + (size_t)b * N_ * 2);

    for (int i = tid; i < N_; i += 256)
        sk[i] = ((uint64_t)f32_ordered(xb[i].x) << 32) | (uint32_t)i;
    __syncthreads();

    const int el = tid & 63;
    const int pt = tid >> 6;
    const uint64_t kown = sk[sg * 64 + el];
    const ulonglong2* sk2 = (const ulonglong2*)sk + pt * 256;
    int cnt = 0;
#pragma unroll 2
    for (int j = 0; j < 256; j += 4) {
        ulonglong2 t0 = sk2[j + 0];
        ulonglong2 t1 = sk2[j + 1];
        ulonglong2 t2 = sk2[j + 2];
        ulonglong2 t3 = sk2[j + 3];
        cnt += (int)(t0.x < kown) + (int)(t0.y < kown)
             + (int)(t1.x < kown) + (int)(t1.y < kown)
             + (int)(t2.x < kown) + (int)(t2.y < kown)
             + (int)(t3.x < kown) + (int)(t3.y < kown);
    }
    pcnt[pt * 64 + el] = cnt;
    __syncthreads();

    if (tid < 64) {
        const int r = pcnt[tid] + pcnt[64 + tid] + pcnt[128 + tid] + pcnt[192 + tid];
        const int i = sg * 64 + tid;
        float2 p = xb[i];
        float sm = p.x * p.x + p.y * p.y;   // no FMA (np sum convention)
        xsorted[(size_t)b * N_ + r] =
            make_float4(p.x, p.y, sm, __uint_as_float((uint32_t)i));
    }
}

// ---- main kernel v11: v8's algorithm with the top-10 list forced into
// NAMED REGISTERS. Evidence: VGPR_Count FELL (64->40->32) as per-thread
// u64 arrays grew -- the rule-#20 signature of arrays living in SCRATCH
// (lambda capture-by-reference defeats SROA). Every insert ladder and merge
// step was round-tripping private memory -> the invariant ~60% stall across
// all 6 structural variants. v11: h0..h9 / t0..t9 named scalars, macros
// instead of lambdas (textual inline, no address-taking, static indexing
// only). Identical comparison/FP order -> output bitwise identical to v8.
// Also keeps v10's free wins: merge#1 writes wcoord; final merge skipped
// (wave-uniform ballot) when phase 2 inserted nothing.
#define D2C(c4v, dcv) { float s_ = sqn + (c4v).z; float pr_ = qx * (c4v).x; \
    float dt_ = __builtin_fmaf(qy, (c4v).y, pr_); \
    float d2_ = __builtin_fmaf(-2.0f, dt_, s_); (dcv) = d2_ > 0.0f ? d2_ : 0.0f; }

// v8 ladder semantics: all compares against PRE-insert values (the loop
// formulation only modified positions j..9 before comparing at j, and the
// j-1 operand was always pre-value), so hoisting all compares is exact.
#define INSERT(dcv, cwv, mv) do { \
    uint64_t key_ = ((uint64_t)__float_as_uint(dcv) << 32) \
                  | (__float_as_uint(cwv) << 11) | (uint32_t)(mv); \
    if (key_ < h9) { \
        bool c0_ = key_ < h0, c1_ = key_ < h1, c2_ = key_ < h2; \
        bool c3_ = key_ < h3, c4_ = key_ < h4, c5_ = key_ < h5; \
        bool c6_ = key_ < h6, c7_ = key_ < h7, c8_ = key_ < h8; \
        h9 = c8_ ? h8 : key_; \
        h8 = c8_ ? (c7_ ? h7 : key_) : h8; \
        h7 = c7_ ? (c6_ ? h6 : key_) : h7; \
        h6 = c6_ ? (c5_ ? h5 : key_) : h6; \
        h5 = c5_ ? (c4_ ? h4 : key_) : h5; \
        h4 = c4_ ? (c3_ ? h3 : key_) : h4; \
        h3 = c3_ ? (c2_ ? h2 : key_) : h3; \
        h2 = c2_ ? (c1_ ? h1 : key_) : h2; \
        h1 = c1_ ? (c0_ ? h0 : key_) : h1; \
        h0 = c0_ ? key_ : h0; \
        h9d  = __uint_as_float((uint32_t)(h9 >> 32)); \
        gate = fminf(h9d, shb); \
        pins = true; \
    } \
} while (0)

#define SCAN_CHUNK(mcv) do { \
    const int m0_ = (mcv) + r; \
    float4 ca_ = xs4[m0_ + 0]; \
    float4 cb_ = xs4[m0_ + 8]; \
    float4 cc_ = xs4[m0_ + 16]; \
    float4 cd_ = xs4[m0_ + 24]; \
    float da_, db_, dc_, dd_; \
    D2C(ca_, da_); D2C(cb_, db_); D2C(cc_, dc_); D2C(cd_, dd_); \
    if (da_ <= gate) INSERT(da_, ca_.w, m0_ + 0); \
    if (db_ <= gate) INSERT(db_, cb_.w, m0_ + 8); \
    if (dc_ <= gate) INSERT(dc_, cc_.w, m0_ + 16); \
    if (dd_ <= gate) INSERT(dd_, cd_.w, m0_ + 24); \
} while (0)

#define BOUNDS(wmv) do { \
    float gb_ = h9d; \
    gb_ = fminf(gb_, __shfl_xor(gb_, 1, 64)); \
    gb_ = fminf(gb_, __shfl_xor(gb_, 2, 64)); \
    gb_ = fminf(gb_, __shfl_xor(gb_, 4, 64)); \
    float hb_ = __uint_as_float((uint32_t)(h1 >> 32)); \
    hb_ = fmaxf(hb_, __shfl_xor(hb_, 1, 64)); \
    hb_ = fmaxf(hb_, __shfl_xor(hb_, 2, 64)); \
    hb_ = fmaxf(hb_, __shfl_xor(hb_, 4, 64)); \
    shb  = fminf(shb, fminf(gb_, hb_)); \
    gate = fminf(h9d, shb); \
    float wm_ = shb; \
    wm_ = fmaxf(wm_, __shfl_xor(wm_, 8,  64)); \
    wm_ = fmaxf(wm_, __shfl_xor(wm_, 16, 64)); \
    wm_ = fmaxf(wm_, __shfl_xor(wm_, 32, 64)); \
    (wmv) = wm_; \
} while (0)

// one selection step of the 8-list merge (lists in lanes (qm, r)); SHIFT
// is the winner's list-pop over named vars; writes wcoord rank (KK-1-sel).
#define SELSTEP(selv, A0,A1,A2,A3,A4,A5,A6,A7,A8,A9) do { \
    uint64_t v_ = A0; \
    uint64_t x_ = (uint64_t)__shfl_xor((unsigned long long)v_, 1, 64); \
    uint64_t m_ = v_ < x_ ? v_ : x_; \
    x_ = (uint64_t)__shfl_xor((unsigned long long)m_, 2, 64); \
    m_ = m_ < x_ ? m_ : x_; \
    x_ = (uint64_t)__shfl_xor((unsigned long long)m_, 4, 64); \
    m_ = m_ < x_ ? m_ : x_; \
    if (v_ == m_) { A0=A1; A1=A2; A2=A3; A3=A4; A4=A5; A5=A6; A6=A7; A7=A8; A8=A9; \
                    A9 = 0xFFFFFFFFFFFFFFFFull; } \
    if (r == 0) { \
        float4 c_ = xs4[(int)(m_ & 0x7FF)]; \
        const int k_ = (KK - 1) - (selv); \
        wcoord[qm * 21 + 2 * k_ + 0] = c_.x; \
        wcoord[qm * 21 + 2 * k_ + 1] = c_.y; \
    } \
    lastv = m_; \
} while (0)

__global__ __launch_bounds__(512, 4) void knn_conv_kernel(
    const float4* __restrict__ xsorted,
    const float* __restrict__ W1,
    const float* __restrict__ weff,
    const float* __restrict__ btot,
    float* __restrict__ out)
{
#pragma clang fp contract(off)
    __shared__ float4 xs4[N_];           // 32 KB
    __shared__ float  wcoord[64 * 21];   //  5.25 KB

    const int tid  = threadIdx.x;
    const int w    = tid >> 6;        // wave 0..7
    const int r    = tid & 7;         // sub-lane: candidate slice
    const int qm   = tid >> 3;        // query within tile (0..63)
    const int b    = blockIdx.x >> 5;
    const int tile = blockIdx.x & 31;

    const float4* xb = xsorted + (size_t)b * N_;
    for (int i = tid; i < N_; i += 512) xs4[i] = xb[i];
    __syncthreads();

    const float4 qv = xs4[tile * 64 + qm];
    const float  qx = qv.x, qy = qv.y, sqn = qv.z;
    const int    gfirst = tile * 64 + w * 8;      // wave's query group
    const float  qa  = xs4[gfirst].x;             // group x-range (uniform)
    const float  qbx = xs4[gfirst + 7].x;

    // sorted-10 of u64 keys in NAMED registers:
    // (d2_bits<<32)|(orig_idx<<11)|sorted_pos
    const uint64_t KINIT = (((uint64_t)0x7F7FFFFFu) << 32) | 0x3FFFFFu;
    uint64_t h0 = KINIT, h1 = KINIT, h2 = KINIT, h3 = KINIT, h4 = KINIT;
    uint64_t h5 = KINIT, h6 = KINIT, h7 = KINIT, h8 = KINIT, h9 = KINIT;
    float h9d  = FLT_MAX;   // 10th-best of own candidate subset
    float shb  = FLT_MAX;   // per-query shared bound (monotone nonincreasing)
    float gate = FLT_MAX;   // fminf(h9d, shb)
    bool  pins = false;     // set by INSERT; reset after phase 1

    // phase 1: home chunk trio (12 candidates/lane >= 10 -> lists full).
    const int home = tile * 2 + (w >> 2);
    int c0s = home - 1;
    if (c0s < 0) c0s = 0;
    if (c0s > NCH - 3) c0s = NCH - 3;
    SCAN_CHUNK((c0s + 0) * SUB);
    SCAN_CHUNK((c0s + 1) * SUB);
    SCAN_CHUNK((c0s + 2) * SUB);

    // merge #1: EXACT union-10th bound (non-destructive over t0..t9) +
    // wcoord writes (winners arrive ascending). Valid: every union-top-10
    // element is retained in its own sub-lane's top-10.
    uint64_t lastv = 0;
    {
        uint64_t t0 = h0, t1 = h1, t2 = h2, t3 = h3, t4 = h4;
        uint64_t t5 = h5, t6 = h6, t7 = h7, t8 = h8, t9 = h9;
        SELSTEP(0, t0,t1,t2,t3,t4,t5,t6,t7,t8,t9);
        SELSTEP(1, t0,t1,t2,t3,t4,t5,t6,t7,t8,t9);
        SELSTEP(2, t0,t1,t2,t3,t4,t5,t6,t7,t8,t9);
        SELSTEP(3, t0,t1,t2,t3,t4,t5,t6,t7,t8,t9);
        SELSTEP(4, t0,t1,t2,t3,t4,t5,t6,t7,t8,t9);
        SELSTEP(5, t0,t1,t2,t3,t4,t5,t6,t7,t8,t9);
        SELSTEP(6, t0,t1,t2,t3,t4,t5,t6,t7,t8,t9);
        SELSTEP(7, t0,t1,t2,t3,t4,t5,t6,t7,t8,t9);
        SELSTEP(8, t0,t1,t2,t3,t4,t5,t6,t7,t8,t9);
        SELSTEP(9, t0,t1,t2,t3,t4,t5,t6,t7,t8,t9);
        shb  = __uint_as_float((uint32_t)(lastv >> 32));
        gate = fminf(h9d, shb);
    }
    pins = false;   // track phase-2 inserts only

    // phase 2: two-pointer outward, step 1, both sides per BOUNDS refresh
    // (stale-wm on the right is conservative: bounds only shrink). Gaps
    // monotone per side -> a failed skip test kills that side for good.
    int  cl = c0s - 1, cr = c0s + 3;
    bool la = (cl >= 0), ra = (cr <= NCH - 1);
    while (la || ra) {
        float wm;
        BOUNDS(wm);
        if (la) {
            float gl = qa - xs4[cl * SUB + SUB - 1].x;            // >= 0
            if (__builtin_fmaf(gl, gl, -4e-6f) > wm) la = false;  // margin >> f32 d2 err
            else { SCAN_CHUNK(cl * SUB); cl -= 1; la = (cl >= 0); }
        }
        if (ra) {
            float gr = xs4[cr * SUB].x - qbx;                     // >= 0
            if (__builtin_fmaf(gr, gr, -4e-6f) > wm) ra = false;
            else { SCAN_CHUNK(cr * SUB); cr += 1; ra = (cr <= NCH - 1); }
        }
    }

    // hoist epilogue weights (latency overlaps merge + barrier)
    const int e = tid & 127;
    float we[20];
    {
        const float4* wp = (const float4*)(weff + e * 20);
#pragma unroll
        for (int rr = 0; rr < 5; ++rr) {
            float4 v = wp[rr];
            we[4 * rr + 0] = v.x; we[4 * rr + 1] = v.y;
            we[4 * rr + 2] = v.z; we[4 * rr + 3] = v.w;
        }
    }
    const float w1x = W1[e * 2 + 0];
    const float w1y = W1[e * 2 + 1];
    const float bt  = btot[e];

    // final merge ONLY if some lane of this wave inserted in phase 2;
    // otherwise wcoord from merge #1 is already the exact final top-10.
    if (__ballot(pins)) {
        SELSTEP(0, h0,h1,h2,h3,h4,h5,h6,h7,h8,h9);
        SELSTEP(1, h0,h1,h2,h3,h4,h5,h6,h7,h8,h9);
        SELSTEP(2, h0,h1,h2,h3,h4,h5,h6,h7,h8,h9);
        SELSTEP(3, h0,h1,h2,h3,h4,h5,h6,h7,h8,h9);
        SELSTEP(4, h0,h1,h2,h3,h4,h5,h6,h7,h8,h9);
        SELSTEP(5, h0,h1,h2,h3,h4,h5,h6,h7,h8,h9);
        SELSTEP(6, h0,h1,h2,h3,h4,h5,h6,h7,h8,h9);
        SELSTEP(7, h0,h1,h2,h3,h4,h5,h6,h7,h8,h9);
        SELSTEP(8, h0,h1,h2,h3,h4,h5,h6,h7,h8,h9);
        SELSTEP(9, h0,h1,h2,h3,h4,h5,h6,h7,h8,h9);
    }
    __syncthreads();

    // epilogue: thread -> channel e; rows scattered to ORIGINAL indices
    // (128 consecutive floats per row, coalesced per wave-store).
    const int qb_ = tid >> 7;
    const size_t obase = (size_t)b * N_ * H_;
#pragma unroll
    for (int jj = 0; jj < 16; ++jj) {
        const int qq = qb_ + 4 * jj;
        float4 xq = xs4[tile * 64 + qq];
        uint32_t orig = __float_as_uint(xq.w);
        const float* wc = &wcoord[qq * 21];
        float acc = bt;
        acc += xq.x * w1x;
        acc += xq.y * w1y;
#pragma unroll
        for (int k = 0; k < KK; ++k) {
            acc += wc[2 * k + 0] * we[2 * k + 0];
            acc += wc[2 * k + 1] * we[2 * k + 1];
        }
        out[obase + (size_t)orig * H_ + e] = acc;
    }
}

extern "C" void kernel_launch(void* const* d_in, const int* in_sizes, int n_in,
                              void* d_out, int out_size, void* d_ws, size_t ws_size,
                              hipStream_t stream) {
    const float* x     = (const float*)d_in[0];
    const float* Wconv = (const float*)d_in[1];
    const float* bconv = (const float*)d_in[2];
    const float* W1    = (const float*)d_in[3];
    const float* b1    = (const float*)d_in[4];
    const float* W2    = (const float*)d_in[5];
    const float* b2    = (const float*)d_in[6];
    float* out  = (float*)d_out;
    float* weff = (float*)d_ws;                           // 2560 floats
    float* btot = weff + H_ * KK * 2;                     // 128 floats
    float4* xsorted = (float4*)((char*)d_ws + 16384);     // 16*2048*16B

    setup_kernel<<<dim3(RANK_BLOCKS + WEFF_BLOCKS), dim3(256), 0, stream>>>(
        x, Wconv, bconv, b1, W2, b2, xsorted, weff, btot);
    knn_conv_kernel<<<dim3(B_ * (N_ / 64)), dim3(512), 0, stream>>>(
        xsorted, W1, weff, btot, out);
}